// Round 7
// baseline (186.319 us; speedup 1.0000x reference)
//
#include <hip/hip_runtime.h>
#include <hip/hip_bf16.h>
#include <math.h>

#define N 8192
#define D 256
#define MARGIN 1.0f

#define BM 128
#define BN 128
#define NCH 4            // k-chunks of 64 bf16 elems (128B per row per plane)
#define NB (N / BM)      // 64
#define NTRI (NB * (NB + 1) / 2)   // 2080 (% 8 == 0)
#define BCAP 64          // class bucket capacity

typedef __attribute__((ext_vector_type(8))) short bhalf8;
typedef __attribute__((ext_vector_type(4))) float f32x4;

__device__ __forceinline__ unsigned short f2bf(float f) {
    return __builtin_bit_cast(unsigned short, __float2bfloat16(f));
}
__device__ __forceinline__ float bf2f(unsigned short u) {
    return __bfloat162float(__builtin_bit_cast(__hip_bfloat16, u));
}

// ---------------------------------------------------------------------------
__global__ void k_zero(int* __restrict__ cnt) {
    cnt[threadIdx.x] = 0;
}

// ---------------------------------------------------------------------------
// split x into hi/lo bf16 planes + build class buckets
// ---------------------------------------------------------------------------
__global__ __launch_bounds__(256) void k_conv(const float* __restrict__ x,
                                              const int* __restrict__ labels,
                                              unsigned short* __restrict__ hi,
                                              unsigned short* __restrict__ lo,
                                              int* __restrict__ cnt,
                                              int* __restrict__ bkt) {
    int i = blockIdx.x * 256 + threadIdx.x;
    float4 v = reinterpret_cast<const float4*>(x)[i];
    ushort4 h, l;
    h.x = f2bf(v.x); l.x = f2bf(v.x - bf2f(h.x));
    h.y = f2bf(v.y); l.y = f2bf(v.y - bf2f(h.y));
    h.z = f2bf(v.z); l.z = f2bf(v.z - bf2f(h.z));
    h.w = f2bf(v.w); l.w = f2bf(v.w - bf2f(h.w));
    reinterpret_cast<ushort4*>(hi)[i] = h;
    reinterpret_cast<ushort4*>(lo)[i] = l;
    if (i < N) {
        int lb = labels[i];
        int p = atomicAdd(&cnt[lb], 1);
        if (p < BCAP) bkt[lb * BCAP + p] = i;
    }
}

// ---------------------------------------------------------------------------
// one wave per anchor; visit only classmates via buckets (exact f32 path)
// ---------------------------------------------------------------------------
__global__ __launch_bounds__(256) void k_dpos(const float* __restrict__ x,
                                              const int* __restrict__ labels,
                                              const int* __restrict__ cnt,
                                              const int* __restrict__ bkt,
                                              float* __restrict__ sq,
                                              float* __restrict__ dpos,
                                              int* __restrict__ minneg,
                                              int* __restrict__ minsemi) {
    int wave = (blockIdx.x * blockDim.x + threadIdx.x) >> 6;
    int lane = threadIdx.x & 63;
    if (wave >= N) return;
    const int i = wave;

    float4 xi = reinterpret_cast<const float4*>(x + (size_t)i * D)[lane];
    float sqi = xi.x * xi.x + xi.y * xi.y + xi.z * xi.z + xi.w * xi.w;
    for (int m = 32; m >= 1; m >>= 1) sqi += __shfl_xor(sqi, m, 64);

    const int L = labels[i];
    int c = cnt[L]; if (c > BCAP) c = BCAP;
    float dp = -1.0f;

    for (int e = 0; e < c; ++e) {
        int j = bkt[L * BCAP + e];
        if (j == i) continue;
        float4 xj = reinterpret_cast<const float4*>(x + (size_t)j * D)[lane];
        float dotp = xi.x * xj.x + xi.y * xj.y + xi.z * xj.z + xi.w * xj.w;
        float sqjp = xj.x * xj.x + xj.y * xj.y + xj.z * xj.z + xj.w * xj.w;
        for (int m = 32; m >= 1; m >>= 1) {
            dotp += __shfl_xor(dotp, m, 64);
            sqjp += __shfl_xor(sqjp, m, 64);
        }
        float sqd = fmaxf(sqi + sqjp - 2.0f * dotp, 0.0f);
        float dist = sqd > 0.0f ? sqrtf(sqd) : 0.0f;
        dp = fmaxf(dp, dist);
    }

    if (lane == 0) {
        sq[i] = sqi;
        dpos[i] = dp;
        minneg[i] = 0x7F800000;
        minsemi[i] = 0x7F800000;
    }
}

// ---------------------------------------------------------------------------
// symmetric bf16-split MFMA GEMM, rotating 3-slot LDS schedule (52 KB).
// ROUND 7 change: XCD-contiguous block remap — each XCD gets a contiguous
// run of triangular tiles, so the shared A-panel (and the B-panel sweep
// window) become L2-resident per XCD instead of scattering across 8 L2s.
// ---------------------------------------------------------------------------
__global__ __launch_bounds__(256) void k_main(const unsigned short* __restrict__ hi,
                                              const unsigned short* __restrict__ lo,
                                              const int* __restrict__ labels,
                                              const float* __restrict__ sq,
                                              const float* __restrict__ dpos,
                                              int* __restrict__ minneg,
                                              int* __restrict__ minsemi) {
    __shared__ char S0[BM * 128];   // 16 KB each, 48 KB total
    __shared__ char S1[BM * 128];
    __shared__ char S2[BM * 128];
    __shared__ float rsq[BM], csq[BN];
    __shared__ float rdp2a[BM], rdp2b[BM], cdp2a[BN], cdp2b[BN];
    __shared__ int rlab[BM], clab[BN];

    const int t = threadIdx.x;
    // XCD-contiguous remap: dispatch round-robins orig%8 across XCDs, so
    // give XCD k the contiguous logical range [k*260, (k+1)*260).
    const int orig = blockIdx.x;
    int tb = (orig & 7) * (NTRI / 8) + (orig >> 3);
    // triangular decode: tb -> (by, bx), by <= bx
    int by = (int)((2 * NB + 1 - sqrtf((float)((2 * NB + 1) * (2 * NB + 1)) -
                                       8.0f * (float)tb)) * 0.5f);
    if (by < 0) by = 0;
    if (by > NB - 1) by = NB - 1;
    while (by > 0 && (by * NB - by * (by - 1) / 2) > tb) --by;
    while (((by + 1) * NB - (by + 1) * by / 2) <= tb) ++by;
    const int bx = by + (tb - (by * NB - by * (by - 1) / 2));
    const int r0 = by * BM, c0 = bx * BN;

    const int w = t >> 6, lane = t & 63;
    const int wr = w >> 1, wc = w & 1;

    if (t < BM) {
        rlab[t] = labels[r0 + t];
        rsq[t] = sq[r0 + t];
        float dp = dpos[r0 + t];
        rdp2a[t] = dp * dp;
        float dh = dp + MARGIN;
        rdp2b[t] = dh * dh;
    } else {
        int u = t - BM;
        clab[u] = labels[c0 + u];
        csq[u] = sq[c0 + u];
        float dp = dpos[c0 + u];
        cdp2a[u] = dp * dp;
        float dh = dp + MARGIN;
        cdp2b[u] = dh * dh;
    }

    f32x4 acc[4][4] = {};

    // staging geometry (r3-proven): 16 chunks of 1KB per buffer; wave w does
    // chunks q*4+w; row = chunk*8 + (lane>>3); 16B slot pre-swizzled in the
    // global source so the LDS dest stays linear. 4 gl_lds per wave per buf.
    const int srow = lane >> 3;
    const int scol = ((lane & 7) ^ srow) << 3;   // k-elem offset (16B units)

#define STAGE1(buf, plane, base, k0e)                                           \
    {                                                                           \
        _Pragma("unroll")                                                       \
        for (int q = 0; q < 4; ++q) {                                           \
            int chunk = q * 4 + w;                                              \
            int row = chunk * 8 + srow;                                         \
            const unsigned short* gp = (plane) + (size_t)((base) + row) * D + (k0e) + scol; \
            char* lp = (buf) + chunk * 1024 + lane * 16;                        \
            __builtin_amdgcn_global_load_lds(                                   \
                (__attribute__((address_space(1))) void*)(void*)gp,             \
                (__attribute__((address_space(3))) void*)lp, 16, 0, 0);         \
        }                                                                       \
    }

    const int g2 = lane >> 4;          // 16B k-subslot / epilogue row group
    const int lr = lane & 15;
    const int rsw = lr & 7;            // row XOR term (rows are +mult of 8)

#define PHASE(PA, PB)                                                           \
    {                                                                           \
        _Pragma("unroll")                                                       \
        for (int kk = 0; kk < 2; ++kk) {                                        \
            bhalf8 aF[4], bF[4];                                                \
            const int cb = kk * 64 + (g2 << 4);                                 \
            _Pragma("unroll")                                                   \
            for (int m = 0; m < 4; ++m) {                                       \
                int ra = wr * 64 + m * 16 + lr;                                 \
                int rb = wc * 64 + m * 16 + lr;                                 \
                aF[m] = *reinterpret_cast<const bhalf8*>((PA) + ra * 128 + (cb ^ (rsw << 4))); \
                bF[m] = *reinterpret_cast<const bhalf8*>((PB) + rb * 128 + (cb ^ (rsw << 4))); \
            }                                                                   \
            _Pragma("unroll")                                                   \
            for (int m = 0; m < 4; ++m)                                         \
                _Pragma("unroll")                                               \
                for (int n = 0; n < 4; ++n)                                     \
                    acc[m][n] = __builtin_amdgcn_mfma_f32_16x16x32_bf16(        \
                        aF[m], bF[n], acc[m][n], 0, 0, 0);                      \
        }                                                                       \
    }

    char* pA = S0;   // Ah(s)   (after hl: Al(s); role swaps with pC each chunk)
    char* pB = S1;   // Bh(s)
    char* pC = S2;   // Bl(s)   (becomes Ah(s+1) carrier)

    STAGE1(pA, hi, r0, 0);      // Ah(0)
    STAGE1(pB, hi, c0, 0);      // Bh(0)
    STAGE1(pC, lo, c0, 0);      // Bl(0)

#pragma unroll 1
    for (int s = 0; s < NCH; ++s) {
        const int k0 = s * 64;

        // === hh: pA(Ah) * pB(Bh). Outstanding: [Ah(4),Bh(4),Bl(4)] -> keep Bl.
        asm volatile("s_waitcnt vmcnt(4)" ::: "memory");
        __builtin_amdgcn_s_barrier();
        PHASE(pA, pB);

        // === hl: pA(Ah) * pC(Bl). Only Bl outstanding.
        asm volatile("s_waitcnt vmcnt(0)" ::: "memory");
        __builtin_amdgcn_s_barrier();
        PHASE(pA, pC);

        // all waves done reading pA/pC -> both slots restageable
        asm volatile("s_waitcnt lgkmcnt(0)" ::: "memory");
        __builtin_amdgcn_sched_barrier(0);
        __builtin_amdgcn_s_barrier();
        STAGE1(pA, lo, r0, k0);                          // Al(s)
        if (s < NCH - 1) STAGE1(pC, hi, r0, k0 + 64);    // Ah(s+1)

        // === lh: pA(Al) * pB(Bh). Wait Al (oldest 4), keep Ah' in flight.
        if (s < NCH - 1)
            asm volatile("s_waitcnt vmcnt(4)" ::: "memory");
        else
            asm volatile("s_waitcnt vmcnt(0)" ::: "memory");
        __builtin_amdgcn_s_barrier();
        PHASE(pA, pB);

        if (s < NCH - 1) {
            // all waves done reading pA/pB -> restage for next chunk
            asm volatile("s_waitcnt lgkmcnt(0)" ::: "memory");
            __builtin_amdgcn_sched_barrier(0);
            __builtin_amdgcn_s_barrier();
            STAGE1(pB, hi, c0, k0 + 64);                 // Bh(s+1)
            STAGE1(pA, lo, c0, k0 + 64);                 // Bl(s+1)
        }
        char* tmp = pA; pA = pC; pC = tmp;               // pA<-Ah', pC<-Bl'
    }
#undef STAGE1
#undef PHASE

    // ---- epilogue: squared-distance space ----
    const float INF = __builtin_inff();

    // row pass: per row, min over this wave's 64 cols
#pragma unroll
    for (int m = 0; m < 4; ++m) {
#pragma unroll
        for (int reg = 0; reg < 4; ++reg) {
            const int row = wr * 64 + m * 16 + g2 * 4 + reg;
            const float si = rsq[row];
            const int rl = rlab[row];
            const float dp2 = rdp2a[row], dphi2 = rdp2b[row];
            float mn = INF, ms = INF;
#pragma unroll
            for (int nn = 0; nn < 4; ++nn) {
                const int col = wc * 64 + nn * 16 + lr;
                float sqd = fmaxf(si + csq[col] - 2.0f * acc[m][nn][reg], 0.0f);
                bool neq = (rl != clab[col]);
                mn = fminf(mn, neq ? sqd : INF);
                bool semi = neq && (sqd > dp2) && (sqd < dphi2);
                ms = fminf(ms, semi ? sqd : INF);
            }
#pragma unroll
            for (int msk = 1; msk <= 8; msk <<= 1) {
                mn = fminf(mn, __shfl_xor(mn, msk, 64));
                ms = fminf(ms, __shfl_xor(ms, msk, 64));
            }
            if (lr == 0) {
                atomicMin(&minneg[r0 + row], __float_as_int(mn));
                atomicMin(&minsemi[r0 + row], __float_as_int(ms));
            }
        }
    }

    // col pass: per col, min over this wave's 64 rows
#pragma unroll
    for (int n = 0; n < 4; ++n) {
        const int col = wc * 64 + n * 16 + lr;
        const float sj = csq[col];
        const int cl = clab[col];
        const float dp2 = cdp2a[col], dphi2 = cdp2b[col];
        float mn = INF, ms = INF;
#pragma unroll
        for (int m = 0; m < 4; ++m) {
#pragma unroll
            for (int reg = 0; reg < 4; ++reg) {
                const int row = wr * 64 + m * 16 + g2 * 4 + reg;
                float sqd = fmaxf(rsq[row] + sj - 2.0f * acc[m][n][reg], 0.0f);
                bool neq = (cl != rlab[row]);
                mn = fminf(mn, neq ? sqd : INF);
                bool semi = neq && (sqd > dp2) && (sqd < dphi2);
                ms = fminf(ms, semi ? sqd : INF);
            }
        }
        mn = fminf(mn, __shfl_xor(mn, 16, 64));
        mn = fminf(mn, __shfl_xor(mn, 32, 64));
        ms = fminf(ms, __shfl_xor(ms, 16, 64));
        ms = fminf(ms, __shfl_xor(ms, 32, 64));
        if (g2 == 0) {
            atomicMin(&minneg[c0 + col], __float_as_int(mn));
            atomicMin(&minsemi[c0 + col], __float_as_int(ms));
        }
    }
}

// ---------------------------------------------------------------------------
// final scalar reduction (minima are SQUARED distances)
// ---------------------------------------------------------------------------
__global__ __launch_bounds__(1024) void k_final(const float* __restrict__ dpos,
                                                const int* __restrict__ minneg,
                                                const int* __restrict__ minsemi,
                                                float* __restrict__ out) {
    __shared__ float ssum[1024];
    __shared__ float scnt[1024];
    int t = threadIdx.x;
    float s = 0.0f, cn = 0.0f;
    for (int i = t; i < N; i += 1024) {
        float dp = dpos[i];
        float mnq = __int_as_float(minneg[i]);
        float msq = __int_as_float(minsemi[i]);
        bool has_pos = dp >= 0.0f;
        bool has_neg = mnq < __builtin_inff();
        if (has_pos && has_neg) {
            float dnq = (msq < __builtin_inff()) ? msq : mnq;
            float dn = sqrtf(dnq);
            s += fmaxf(dp - dn + MARGIN, 0.0f);
            cn += 1.0f;
        }
    }
    ssum[t] = s;
    scnt[t] = cn;
    __syncthreads();
    for (int off = 512; off >= 1; off >>= 1) {
        if (t < off) {
            ssum[t] += ssum[t + off];
            scnt[t] += scnt[t + off];
        }
        __syncthreads();
    }
    if (t == 0) out[0] = ssum[0] / scnt[0];
}

// ---------------------------------------------------------------------------
extern "C" void kernel_launch(void* const* d_in, const int* in_sizes, int n_in,
                              void* d_out, int out_size, void* d_ws, size_t ws_size,
                              hipStream_t stream) {
    const float* x = (const float*)d_in[0];
    const int* labels = (const int*)d_in[1];
    float* out = (float*)d_out;

    // ws: sq[N] | dpos[N] | minneg[N] | minsemi[N] | cnt[512] | bkt[512*64]
    //     | hi[N*D] bf16 | lo[N*D] bf16
    float* sq = (float*)d_ws;
    float* dpos = sq + N;
    int* minneg = (int*)(dpos + N);
    int* minsemi = minneg + N;
    int* cnt = minsemi + N;
    int* bkt = cnt + 512;
    unsigned short* hi = (unsigned short*)(bkt + 512 * BCAP);
    unsigned short* lo = hi + (size_t)N * D;

    hipLaunchKernelGGL(k_zero, dim3(1), dim3(512), 0, stream, cnt);
    hipLaunchKernelGGL(k_conv, dim3(N * D / 4 / 256), dim3(256), 0, stream,
                       x, labels, hi, lo, cnt, bkt);
    hipLaunchKernelGGL(k_dpos, dim3(N / 4), dim3(256), 0, stream,
                       x, labels, cnt, bkt, sq, dpos, minneg, minsemi);
    hipLaunchKernelGGL(k_main, dim3(NTRI), dim3(256), 0, stream,
                       hi, lo, labels, sq, dpos, minneg, minsemi);
    hipLaunchKernelGGL(k_final, dim3(1), dim3(1024), 0, stream,
                       dpos, minneg, minsemi, out);
}

// Round 8
// 172.586 us; speedup vs baseline: 1.0796x; 1.0796x over previous
//
#include <hip/hip_runtime.h>
#include <hip/hip_bf16.h>
#include <math.h>

#define N 8192
#define D 256
#define MARGIN 1.0f

#define BM 128
#define BN 128
#define NCH 4            // K-chunks of 64 fp16 elems (128B per row)
#define NB (N / BM)      // 64
#define NTRI (NB * (NB + 1) / 2)   // 2080
#define BCAP 64          // class bucket capacity

typedef __attribute__((ext_vector_type(8))) _Float16 half8;
typedef __attribute__((ext_vector_type(4))) _Float16 half4;
typedef __attribute__((ext_vector_type(4))) float f32x4;
typedef unsigned long long ull;

#define KEY_INIT 0x7F800000FFFFFFFFULL   // +inf | idx=all-ones

// ---------------------------------------------------------------------------
// k_conv: f32 -> fp16 plane + class buckets.
// ---------------------------------------------------------------------------
__global__ __launch_bounds__(256) void k_conv(const float* __restrict__ x,
                                              const int* __restrict__ labels,
                                              _Float16* __restrict__ hp,
                                              int* __restrict__ cnt,
                                              int* __restrict__ bkt) {
    int i = blockIdx.x * 256 + threadIdx.x;
    float4 v = reinterpret_cast<const float4*>(x)[i];
    half4 h;
    h[0] = (_Float16)v.x; h[1] = (_Float16)v.y;
    h[2] = (_Float16)v.z; h[3] = (_Float16)v.w;
    reinterpret_cast<half4*>(hp)[i] = h;
    if (i < N) {
        int lb = labels[i];
        int p = atomicAdd(&cnt[lb], 1);
        if (p < BCAP) bkt[lb * BCAP + p] = i;
    }
}

// ---------------------------------------------------------------------------
// k_dpos: one wave per anchor; exact f32 d_pos via class buckets.
// ---------------------------------------------------------------------------
__global__ __launch_bounds__(256) void k_dpos(const float* __restrict__ x,
                                              const int* __restrict__ labels,
                                              const int* __restrict__ cnt,
                                              const int* __restrict__ bkt,
                                              float* __restrict__ sq,
                                              float* __restrict__ dpos,
                                              ull* __restrict__ minneg,
                                              ull* __restrict__ minsemi) {
    int wave = (blockIdx.x * blockDim.x + threadIdx.x) >> 6;
    int lane = threadIdx.x & 63;
    if (wave >= N) return;
    const int i = wave;

    float4 xi = reinterpret_cast<const float4*>(x + (size_t)i * D)[lane];
    float sqi = xi.x * xi.x + xi.y * xi.y + xi.z * xi.z + xi.w * xi.w;
    for (int m = 32; m >= 1; m >>= 1) sqi += __shfl_xor(sqi, m, 64);

    const int L = labels[i];
    int c = cnt[L]; if (c > BCAP) c = BCAP;
    float dp = -1.0f;

    for (int e = 0; e < c; ++e) {
        int j = bkt[L * BCAP + e];
        if (j == i) continue;
        float4 xj = reinterpret_cast<const float4*>(x + (size_t)j * D)[lane];
        float dotp = xi.x * xj.x + xi.y * xj.y + xi.z * xj.z + xi.w * xj.w;
        float sqjp = xj.x * xj.x + xj.y * xj.y + xj.z * xj.z + xj.w * xj.w;
        for (int m = 32; m >= 1; m >>= 1) {
            dotp += __shfl_xor(dotp, m, 64);
            sqjp += __shfl_xor(sqjp, m, 64);
        }
        float sqd = fmaxf(sqi + sqjp - 2.0f * dotp, 0.0f);
        float dist = sqd > 0.0f ? sqrtf(sqd) : 0.0f;
        dp = fmaxf(dp, dist);
    }

    if (lane == 0) {
        sq[i] = sqi;
        dpos[i] = dp;
        minneg[i] = KEY_INIT;
        minsemi[i] = KEY_INIT;
    }
}

// ---------------------------------------------------------------------------
// k_main: symmetric fp16 MFMA GEMM (single plane) + fused semi-hard epilogue.
// Triangular tiles; 128x128, 4 waves, K=256 in 4 chunks of 64; double-
// buffered A/B (64 KB LDS); stage-issue-early then one __syncthreads per
// chunk. r3-proven 0-conflict XOR swizzle (linear gl_lds dest, pre-swizzled
// global source, same XOR on ds_read). Epilogue mins carry packed
// (sqd_bits<<32)|index 64-bit keys -> deterministic argmin via atomicMin.
// ---------------------------------------------------------------------------
__global__ __launch_bounds__(256) void k_main(const _Float16* __restrict__ hp,
                                              const int* __restrict__ labels,
                                              const float* __restrict__ sq,
                                              const float* __restrict__ dpos,
                                              ull* __restrict__ minneg,
                                              ull* __restrict__ minsemi) {
    __shared__ char Abuf[2][BM * 128];   // 16 KB each
    __shared__ char Bbuf[2][BN * 128];
    __shared__ float rsq[BM], csq[BN];
    __shared__ float rdp2a[BM], rdp2b[BM], cdp2a[BN], cdp2b[BN];
    __shared__ int rlab[BM], clab[BN];

    const int t = threadIdx.x;
    int tb = blockIdx.x;
    // triangular decode: tb -> (by, bx), by <= bx
    int by = (int)((2 * NB + 1 - sqrtf((float)((2 * NB + 1) * (2 * NB + 1)) -
                                       8.0f * (float)tb)) * 0.5f);
    if (by < 0) by = 0;
    if (by > NB - 1) by = NB - 1;
    while (by > 0 && (by * NB - by * (by - 1) / 2) > tb) --by;
    while (((by + 1) * NB - (by + 1) * by / 2) <= tb) ++by;
    const int bx = by + (tb - (by * NB - by * (by - 1) / 2));
    const int r0 = by * BM, c0 = bx * BN;

    const int w = t >> 6, lane = t & 63;
    const int wr = w >> 1, wc = w & 1;

    if (t < BM) {
        rlab[t] = labels[r0 + t];
        rsq[t] = sq[r0 + t];
        float dp = dpos[r0 + t];
        rdp2a[t] = dp * dp;          // dp=-1 sentinel -> (1,0): semi never true
        float dh = dp + MARGIN;
        rdp2b[t] = dh * dh;
    } else {
        int u = t - BM;
        clab[u] = labels[c0 + u];
        csq[u] = sq[c0 + u];
        float dp = dpos[c0 + u];
        cdp2a[u] = dp * dp;
        float dh = dp + MARGIN;
        cdp2b[u] = dh * dh;
    }

    f32x4 acc[4][4] = {};

    // staging geometry: 16 chunks of 1KB per buffer; wave w writes chunks
    // q*4+w; row = chunk*8 + (lane>>3); lane's 16B slot pre-swizzled in the
    // global source; LDS dest linear.
    const int srow = lane >> 3;
    const int scol = ((lane & 7) ^ srow) << 3;   // fp16-elem offset (16B units)

#define STAGE(bufA, bufB, k0e)                                                  \
    {                                                                           \
        _Pragma("unroll")                                                       \
        for (int q = 0; q < 4; ++q) {                                           \
            int chunk = q * 4 + w;                                              \
            int row = chunk * 8 + srow;                                         \
            const _Float16* gpa = hp + (size_t)(r0 + row) * D + (k0e) + scol;   \
            const _Float16* gpb = hp + (size_t)(c0 + row) * D + (k0e) + scol;   \
            char* lpa = (bufA) + chunk * 1024 + lane * 16;                      \
            char* lpb = (bufB) + chunk * 1024 + lane * 16;                      \
            __builtin_amdgcn_global_load_lds(                                   \
                (__attribute__((address_space(1))) void*)(void*)gpa,            \
                (__attribute__((address_space(3))) void*)lpa, 16, 0, 0);        \
            __builtin_amdgcn_global_load_lds(                                   \
                (__attribute__((address_space(1))) void*)(void*)gpb,            \
                (__attribute__((address_space(3))) void*)lpb, 16, 0, 0);        \
        }                                                                       \
    }

    STAGE(Abuf[0], Bbuf[0], 0);
    asm volatile("s_waitcnt vmcnt(0)" ::: "memory");
    __syncthreads();

    const int g2 = lane >> 4;          // 16B k-subslot / epilogue row group
    const int lr = lane & 15;
    const int rsw = lr & 7;            // row XOR term (rows offset by mult of 8)

#pragma unroll 1
    for (int s = 0; s < NCH; ++s) {
        const int cur = s & 1;
        if (s < NCH - 1) STAGE(Abuf[cur ^ 1], Bbuf[cur ^ 1], (s + 1) * 64);

#pragma unroll
        for (int kk = 0; kk < 2; ++kk) {
            const int cb = kk * 64 + (g2 << 4);
            half8 aF[4], bF[4];
#pragma unroll
            for (int m = 0; m < 4; ++m) {
                int ra = wr * 64 + m * 16 + lr;
                int rb = wc * 64 + m * 16 + lr;
                aF[m] = *reinterpret_cast<const half8*>(
                    Abuf[cur] + ra * 128 + (cb ^ (rsw << 4)));
                bF[m] = *reinterpret_cast<const half8*>(
                    Bbuf[cur] + rb * 128 + (cb ^ (rsw << 4)));
            }
#pragma unroll
            for (int m = 0; m < 4; ++m)
#pragma unroll
                for (int n = 0; n < 4; ++n)
                    acc[m][n] = __builtin_amdgcn_mfma_f32_16x16x32_f16(
                        aF[m], bF[n], acc[m][n], 0, 0, 0);
        }
        __syncthreads();   // drains vmcnt+lgkmcnt; next chunk may overwrite cur
    }
#undef STAGE

    // ---- epilogue: squared-distance space, packed (value|index) keys ----
    const float INF = __builtin_inff();

    // row pass: per row, min over this wave's 64 cols
#pragma unroll
    for (int m = 0; m < 4; ++m) {
#pragma unroll
        for (int reg = 0; reg < 4; ++reg) {
            const int row = wr * 64 + m * 16 + g2 * 4 + reg;
            const float si = rsq[row];
            const int rl = rlab[row];
            const float dp2 = rdp2a[row], dphi2 = rdp2b[row];
            ull kn = KEY_INIT, ks = KEY_INIT;
#pragma unroll
            for (int nn = 0; nn < 4; ++nn) {
                const int col = wc * 64 + nn * 16 + lr;
                float sqd = fmaxf(si + csq[col] - 2.0f * acc[m][nn][reg], 0.0f);
                if (rl != clab[col]) {
                    ull key = ((ull)__float_as_uint(sqd) << 32) | (unsigned)(c0 + col);
                    kn = kn < key ? kn : key;
                    if (sqd > dp2 && sqd < dphi2) ks = ks < key ? ks : key;
                }
            }
#pragma unroll
            for (int msk = 1; msk <= 8; msk <<= 1) {
                ull on = __shfl_xor(kn, msk, 64);
                ull os = __shfl_xor(ks, msk, 64);
                kn = kn < on ? kn : on;
                ks = ks < os ? ks : os;
            }
            if (lr == 0) {
                if (kn != KEY_INIT) atomicMin(&minneg[r0 + row], kn);
                if (ks != KEY_INIT) atomicMin(&minsemi[r0 + row], ks);
            }
        }
    }

    // col pass: per col, min over this wave's 64 rows
#pragma unroll
    for (int n = 0; n < 4; ++n) {
        const int col = wc * 64 + n * 16 + lr;
        const float sj = csq[col];
        const int cl = clab[col];
        const float dp2 = cdp2a[col], dphi2 = cdp2b[col];
        ull kn = KEY_INIT, ks = KEY_INIT;
#pragma unroll
        for (int m = 0; m < 4; ++m) {
#pragma unroll
            for (int reg = 0; reg < 4; ++reg) {
                const int row = wr * 64 + m * 16 + g2 * 4 + reg;
                float sqd = fmaxf(rsq[row] + sj - 2.0f * acc[m][n][reg], 0.0f);
                if (cl != rlab[row]) {
                    ull key = ((ull)__float_as_uint(sqd) << 32) | (unsigned)(r0 + row);
                    kn = kn < key ? kn : key;
                    if (sqd > dp2 && sqd < dphi2) ks = ks < key ? ks : key;
                }
            }
        }
        {
            ull on = __shfl_xor(kn, 16, 64); kn = kn < on ? kn : on;
            on = __shfl_xor(kn, 32, 64);     kn = kn < on ? kn : on;
            ull os = __shfl_xor(ks, 16, 64); ks = ks < os ? ks : os;
            os = __shfl_xor(ks, 32, 64);     ks = ks < os ? ks : os;
        }
        if (g2 == 0) {
            if (kn != KEY_INIT) atomicMin(&minneg[c0 + col], kn);
            if (ks != KEY_INIT) atomicMin(&minsemi[c0 + col], ks);
        }
    }
    (void)INF;
}

// ---------------------------------------------------------------------------
// k_exact: one wave per anchor; re-compute the SELECTED pair's distance
// exactly in f32, emit per-anchor loss and validity.
// ---------------------------------------------------------------------------
__global__ __launch_bounds__(256) void k_exact(const float* __restrict__ x,
                                               const float* __restrict__ sq,
                                               const float* __restrict__ dpos,
                                               const ull* __restrict__ minneg,
                                               const ull* __restrict__ minsemi,
                                               float* __restrict__ loss,
                                               float* __restrict__ valid) {
    int wave = (blockIdx.x * blockDim.x + threadIdx.x) >> 6;
    int lane = threadIdx.x & 63;
    if (wave >= N) return;
    const int i = wave;

    ull kn = minneg[i], ks = minsemi[i];
    bool has_neg = (kn >> 32) != 0x7F800000ULL;
    bool has_semi = (ks >> 32) != 0x7F800000ULL;
    float dp = dpos[i];
    bool has_pos = dp >= 0.0f;

    float l = 0.0f, v = 0.0f;
    if (has_pos && has_neg) {
        int j = (int)((has_semi ? ks : kn) & 0xFFFFFFFFULL);
        float4 xi = reinterpret_cast<const float4*>(x + (size_t)i * D)[lane];
        float4 xj = reinterpret_cast<const float4*>(x + (size_t)j * D)[lane];
        float dotp = xi.x * xj.x + xi.y * xj.y + xi.z * xj.z + xi.w * xj.w;
        for (int m = 32; m >= 1; m >>= 1) dotp += __shfl_xor(dotp, m, 64);
        float sqd = fmaxf(sq[i] + sq[j] - 2.0f * dotp, 0.0f);
        float dn = sqd > 0.0f ? sqrtf(sqd) : 0.0f;
        l = fmaxf(dp - dn + MARGIN, 0.0f);
        v = 1.0f;
    }
    if (lane == 0) {
        loss[i] = l;
        valid[i] = v;
    }
}

// ---------------------------------------------------------------------------
// k_final: deterministic tree sum of loss/valid -> scalar.
// ---------------------------------------------------------------------------
__global__ __launch_bounds__(1024) void k_final(const float* __restrict__ loss,
                                                const float* __restrict__ valid,
                                                float* __restrict__ out) {
    __shared__ float ssum[1024];
    __shared__ float scnt[1024];
    int t = threadIdx.x;
    float s = 0.0f, cn = 0.0f;
    for (int i = t; i < N; i += 1024) {
        s += loss[i];
        cn += valid[i];
    }
    ssum[t] = s;
    scnt[t] = cn;
    __syncthreads();
    for (int off = 512; off >= 1; off >>= 1) {
        if (t < off) {
            ssum[t] += ssum[t + off];
            scnt[t] += scnt[t + off];
        }
        __syncthreads();
    }
    if (t == 0) out[0] = ssum[0] / scnt[0];
}

// ---------------------------------------------------------------------------
extern "C" void kernel_launch(void* const* d_in, const int* in_sizes, int n_in,
                              void* d_out, int out_size, void* d_ws, size_t ws_size,
                              hipStream_t stream) {
    const float* x = (const float*)d_in[0];
    const int* labels = (const int*)d_in[1];
    float* out = (float*)d_out;

    // ws: sq[N] | dpos[N] | minneg[N] ull | minsemi[N] ull | loss[N] | valid[N]
    //     | cnt[512] | bkt[512*64] | hp[N*D] fp16
    float* sq = (float*)d_ws;
    float* dpos = sq + N;
    ull* minneg = (ull*)(dpos + N);          // 8B aligned (offset 64 KB)
    ull* minsemi = minneg + N;
    float* loss = (float*)(minsemi + N);
    float* valid = loss + N;
    int* cnt = (int*)(valid + N);
    int* bkt = cnt + 512;
    _Float16* hp = (_Float16*)(bkt + 512 * BCAP);

    hipMemsetAsync(cnt, 0, 512 * sizeof(int), stream);
    hipLaunchKernelGGL(k_conv, dim3(N * D / 4 / 256), dim3(256), 0, stream,
                       x, labels, hp, cnt, bkt);
    hipLaunchKernelGGL(k_dpos, dim3(N / 4), dim3(256), 0, stream,
                       x, labels, cnt, bkt, sq, dpos, minneg, minsemi);
    hipLaunchKernelGGL(k_main, dim3(NTRI), dim3(256), 0, stream,
                       hp, labels, sq, dpos, minneg, minsemi);
    hipLaunchKernelGGL(k_exact, dim3(N / 4), dim3(256), 0, stream,
                       x, sq, dpos, minneg, minsemi, loss, valid);
    hipLaunchKernelGGL(k_final, dim3(1), dim3(1024), 0, stream,
                       loss, valid, out);
}

// Round 9
// 133.226 us; speedup vs baseline: 1.3985x; 1.2954x over previous
//
#include <hip/hip_runtime.h>
#include <hip/hip_bf16.h>
#include <math.h>

#define N 8192
#define D 256
#define MARGIN 1.0f

#define BM 128
#define BN 128
#define NCH 4            // K-chunks of 64 fp16 elems (128B per row)
#define NB (N / BM)      // 64
#define NTRI (NB * (NB + 1) / 2)   // 2080
#define BCAP 64          // class bucket capacity

#define KINIT 0xFFFFFFFFu
#define QSCALE 131072.0f         // 2^17; sqd<=4 -> q < 2^19
#define QMAX 524287.0f           // 2^19 - 1
#define IDXMASK 0x1FFFu          // 13 bits (N=8192)

typedef __attribute__((ext_vector_type(8))) _Float16 half8;
typedef __attribute__((ext_vector_type(4))) _Float16 half4;
typedef __attribute__((ext_vector_type(4))) float f32x4;
typedef unsigned int uint32;

__device__ __forceinline__ uint32 minu(uint32 a, uint32 b) { return a < b ? a : b; }

// ---------------------------------------------------------------------------
// k_conv: f32 -> fp16 plane + class buckets.
// ---------------------------------------------------------------------------
__global__ __launch_bounds__(256) void k_conv(const float* __restrict__ x,
                                              const int* __restrict__ labels,
                                              _Float16* __restrict__ hp,
                                              int* __restrict__ cnt,
                                              int* __restrict__ bkt) {
    int i = blockIdx.x * 256 + threadIdx.x;
    float4 v = reinterpret_cast<const float4*>(x)[i];
    half4 h;
    h[0] = (_Float16)v.x; h[1] = (_Float16)v.y;
    h[2] = (_Float16)v.z; h[3] = (_Float16)v.w;
    reinterpret_cast<half4*>(hp)[i] = h;
    if (i < N) {
        int lb = labels[i];
        int p = atomicAdd(&cnt[lb], 1);
        if (p < BCAP) bkt[lb * BCAP + p] = i;
    }
}

// ---------------------------------------------------------------------------
// k_dpos: one wave per anchor; exact f32 d_pos via class buckets.
// ---------------------------------------------------------------------------
__global__ __launch_bounds__(256) void k_dpos(const float* __restrict__ x,
                                              const int* __restrict__ labels,
                                              const int* __restrict__ cnt,
                                              const int* __restrict__ bkt,
                                              float* __restrict__ sq,
                                              float* __restrict__ dpos) {
    int wave = (blockIdx.x * blockDim.x + threadIdx.x) >> 6;
    int lane = threadIdx.x & 63;
    if (wave >= N) return;
    const int i = wave;

    float4 xi = reinterpret_cast<const float4*>(x + (size_t)i * D)[lane];
    float sqi = xi.x * xi.x + xi.y * xi.y + xi.z * xi.z + xi.w * xi.w;
    for (int m = 32; m >= 1; m >>= 1) sqi += __shfl_xor(sqi, m, 64);

    const int L = labels[i];
    int c = cnt[L]; if (c > BCAP) c = BCAP;
    float dp = -1.0f;

    for (int e = 0; e < c; ++e) {
        int j = bkt[L * BCAP + e];
        if (j == i) continue;
        float4 xj = reinterpret_cast<const float4*>(x + (size_t)j * D)[lane];
        float dotp = xi.x * xj.x + xi.y * xj.y + xi.z * xj.z + xi.w * xj.w;
        float sqjp = xj.x * xj.x + xj.y * xj.y + xj.z * xj.z + xj.w * xj.w;
        for (int m = 32; m >= 1; m >>= 1) {
            dotp += __shfl_xor(dotp, m, 64);
            sqjp += __shfl_xor(sqjp, m, 64);
        }
        float sqd = fmaxf(sqi + sqjp - 2.0f * dotp, 0.0f);
        float dist = sqd > 0.0f ? sqrtf(sqd) : 0.0f;
        dp = fmaxf(dp, dist);
    }

    if (lane == 0) {
        sq[i] = sqi;
        dpos[i] = dp;
    }
}

// ---------------------------------------------------------------------------
// k_main: symmetric fp16 MFMA GEMM + fused epilogue with ZERO global atomics.
// GEMM core identical to r8 (proven): 128x128 triangular tiles, dbuf BK=64,
// linear gl_lds dest + pre-swizzled source + XOR'd ds_read (0 conflicts).
// Epilogue: 32-bit fixed-point keys (q(sqd)<<13 | idx), wave shuffle-reduce,
// in-LDS combine of the two waves sharing a row/col, then PLAIN STORES of
// per-tile partial minima to pr_*/pc_* (each line written once -> no cross-
// XCD atomic ping-pong).
// ---------------------------------------------------------------------------
__global__ __launch_bounds__(256) void k_main(const _Float16* __restrict__ hp,
                                              const int* __restrict__ labels,
                                              const float* __restrict__ sq,
                                              const float* __restrict__ dpos,
                                              uint32* __restrict__ pr_n,
                                              uint32* __restrict__ pr_s,
                                              uint32* __restrict__ pc_n,
                                              uint32* __restrict__ pc_s) {
    __shared__ char Abuf[2][BM * 128];   // 16 KB each
    __shared__ char Bbuf[2][BN * 128];
    __shared__ float rsq[BM], csq[BN];
    __shared__ float rdp2a[BM], rdp2b[BM], cdp2a[BN], cdp2b[BN];
    __shared__ int rlab[BM], clab[BN];
    __shared__ uint32 tmpn[2][BM], tmps[2][BM];   // cross-wave combine buffers

    const int t = threadIdx.x;
    int tb = blockIdx.x;
    // triangular decode: tb -> (by, bx), by <= bx
    int by = (int)((2 * NB + 1 - sqrtf((float)((2 * NB + 1) * (2 * NB + 1)) -
                                       8.0f * (float)tb)) * 0.5f);
    if (by < 0) by = 0;
    if (by > NB - 1) by = NB - 1;
    while (by > 0 && (by * NB - by * (by - 1) / 2) > tb) --by;
    while (((by + 1) * NB - (by + 1) * by / 2) <= tb) ++by;
    const int bx = by + (tb - (by * NB - by * (by - 1) / 2));
    const int r0 = by * BM, c0 = bx * BN;

    const int w = t >> 6, lane = t & 63;
    const int wr = w >> 1, wc = w & 1;

    if (t < BM) {
        rlab[t] = labels[r0 + t];
        rsq[t] = sq[r0 + t];
        float dp = dpos[r0 + t];
        rdp2a[t] = dp * dp;          // dp=-1 sentinel -> (1,0): semi never true
        float dh = dp + MARGIN;
        rdp2b[t] = dh * dh;
    } else {
        int u = t - BM;
        clab[u] = labels[c0 + u];
        csq[u] = sq[c0 + u];
        float dp = dpos[c0 + u];
        cdp2a[u] = dp * dp;
        float dh = dp + MARGIN;
        cdp2b[u] = dh * dh;
    }

    f32x4 acc[4][4] = {};

    const int srow = lane >> 3;
    const int scol = ((lane & 7) ^ srow) << 3;   // fp16-elem offset (16B units)

#define STAGE(bufA, bufB, k0e)                                                  \
    {                                                                           \
        _Pragma("unroll")                                                       \
        for (int q = 0; q < 4; ++q) {                                           \
            int chunk = q * 4 + w;                                              \
            int row = chunk * 8 + srow;                                         \
            const _Float16* gpa = hp + (size_t)(r0 + row) * D + (k0e) + scol;   \
            const _Float16* gpb = hp + (size_t)(c0 + row) * D + (k0e) + scol;   \
            char* lpa = (bufA) + chunk * 1024 + lane * 16;                      \
            char* lpb = (bufB) + chunk * 1024 + lane * 16;                      \
            __builtin_amdgcn_global_load_lds(                                   \
                (__attribute__((address_space(1))) void*)(void*)gpa,            \
                (__attribute__((address_space(3))) void*)lpa, 16, 0, 0);        \
            __builtin_amdgcn_global_load_lds(                                   \
                (__attribute__((address_space(1))) void*)(void*)gpb,            \
                (__attribute__((address_space(3))) void*)lpb, 16, 0, 0);        \
        }                                                                       \
    }

    STAGE(Abuf[0], Bbuf[0], 0);
    asm volatile("s_waitcnt vmcnt(0)" ::: "memory");
    __syncthreads();

    const int g2 = lane >> 4;
    const int lr = lane & 15;
    const int rsw = lr & 7;

#pragma unroll 1
    for (int s = 0; s < NCH; ++s) {
        const int cur = s & 1;
        if (s < NCH - 1) STAGE(Abuf[cur ^ 1], Bbuf[cur ^ 1], (s + 1) * 64);

#pragma unroll
        for (int kk = 0; kk < 2; ++kk) {
            const int cb = kk * 64 + (g2 << 4);
            half8 aF[4], bF[4];
#pragma unroll
            for (int m = 0; m < 4; ++m) {
                int ra = wr * 64 + m * 16 + lr;
                int rb = wc * 64 + m * 16 + lr;
                aF[m] = *reinterpret_cast<const half8*>(
                    Abuf[cur] + ra * 128 + (cb ^ (rsw << 4)));
                bF[m] = *reinterpret_cast<const half8*>(
                    Bbuf[cur] + rb * 128 + (cb ^ (rsw << 4)));
            }
#pragma unroll
            for (int m = 0; m < 4; ++m)
#pragma unroll
                for (int n = 0; n < 4; ++n)
                    acc[m][n] = __builtin_amdgcn_mfma_f32_16x16x32_f16(
                        aF[m], bF[n], acc[m][n], 0, 0, 0);
        }
        __syncthreads();
    }
#undef STAGE

    // ---- epilogue: 32-bit keys, shuffle reduce, LDS combine, plain stores --

    // row pass: per row, min over this wave's 64 cols
#pragma unroll
    for (int m = 0; m < 4; ++m) {
#pragma unroll
        for (int reg = 0; reg < 4; ++reg) {
            const int row = wr * 64 + m * 16 + g2 * 4 + reg;
            const float si = rsq[row];
            const int rl = rlab[row];
            const float dp2 = rdp2a[row], dphi2 = rdp2b[row];
            uint32 kn = KINIT, ks = KINIT;
#pragma unroll
            for (int nn = 0; nn < 4; ++nn) {
                const int col = wc * 64 + nn * 16 + lr;
                float sqd = fmaxf(si + csq[col] - 2.0f * acc[m][nn][reg], 0.0f);
                uint32 key = ((uint32)fminf(sqd * QSCALE, QMAX) << 13) |
                             (uint32)(c0 + col);
                bool neq = (rl != clab[col]);
                kn = minu(kn, neq ? key : KINIT);
                bool semi = neq && (sqd > dp2) && (sqd < dphi2);
                ks = minu(ks, semi ? key : KINIT);
            }
#pragma unroll
            for (int msk = 1; msk <= 8; msk <<= 1) {
                kn = minu(kn, (uint32)__shfl_xor((int)kn, msk, 64));
                ks = minu(ks, (uint32)__shfl_xor((int)ks, msk, 64));
            }
            if (lr == 0) {
                tmpn[wc][row] = kn;
                tmps[wc][row] = ks;
            }
        }
    }
    __syncthreads();
    if (t < BM) {
        pr_n[(size_t)tb * BM + t] = minu(tmpn[0][t], tmpn[1][t]);
        pr_s[(size_t)tb * BM + t] = minu(tmps[0][t], tmps[1][t]);
    }
    __syncthreads();

    // col pass: per col, min over this wave's 64 rows
#pragma unroll
    for (int n = 0; n < 4; ++n) {
        const int col = wc * 64 + n * 16 + lr;
        const float sj = csq[col];
        const int cl = clab[col];
        const float dp2 = cdp2a[col], dphi2 = cdp2b[col];
        uint32 kn = KINIT, ks = KINIT;
#pragma unroll
        for (int m = 0; m < 4; ++m) {
#pragma unroll
            for (int reg = 0; reg < 4; ++reg) {
                const int row = wr * 64 + m * 16 + g2 * 4 + reg;
                float sqd = fmaxf(rsq[row] + sj - 2.0f * acc[m][n][reg], 0.0f);
                uint32 key = ((uint32)fminf(sqd * QSCALE, QMAX) << 13) |
                             (uint32)(r0 + row);
                bool neq = (cl != rlab[row]);
                kn = minu(kn, neq ? key : KINIT);
                bool semi = neq && (sqd > dp2) && (sqd < dphi2);
                ks = minu(ks, semi ? key : KINIT);
            }
        }
        kn = minu(kn, (uint32)__shfl_xor((int)kn, 16, 64));
        kn = minu(kn, (uint32)__shfl_xor((int)kn, 32, 64));
        ks = minu(ks, (uint32)__shfl_xor((int)ks, 16, 64));
        ks = minu(ks, (uint32)__shfl_xor((int)ks, 32, 64));
        if (g2 == 0) {
            tmpn[wr][col] = kn;
            tmps[wr][col] = ks;
        }
    }
    __syncthreads();
    if (t < BN) {
        pc_n[(size_t)tb * BN + t] = minu(tmpn[0][t], tmpn[1][t]);
        pc_s[(size_t)tb * BN + t] = minu(tmps[0][t], tmps[1][t]);
    }
}

// ---------------------------------------------------------------------------
// k_reduce: fold per-tile partials into per-anchor keys. One thread/anchor;
// anchor i (q=i/128) appears as a ROW in tiles (q,bx) bx>=q (consecutive tb)
// and as a COL in tiles (by,q) by<=q. 65 tiles total. Coalesced loads.
// ---------------------------------------------------------------------------
__global__ __launch_bounds__(256) void k_reduce(const uint32* __restrict__ pr_n,
                                                const uint32* __restrict__ pr_s,
                                                const uint32* __restrict__ pc_n,
                                                const uint32* __restrict__ pc_s,
                                                uint32* __restrict__ kn_out,
                                                uint32* __restrict__ ks_out) {
    int i = blockIdx.x * 256 + threadIdx.x;
    int q = i >> 7, r = i & 127;
    uint32 kn = KINIT, ks = KINIT;

    int base = q * NB - q * (q - 1) / 2;   // first tile of row q
#pragma unroll 8
    for (int k = 0; k < NB - q; ++k) {
        size_t off = (size_t)(base + k) * BM + r;
        kn = minu(kn, pr_n[off]);
        ks = minu(ks, pr_s[off]);
    }
    int b2 = 0;
#pragma unroll 8
    for (int byy = 0; byy <= q; ++byy) {
        size_t off = (size_t)(b2 + (q - byy)) * BN + r;
        kn = minu(kn, pc_n[off]);
        ks = minu(ks, pc_s[off]);
        b2 += NB - byy;
    }
    kn_out[i] = kn;
    ks_out[i] = ks;
}

// ---------------------------------------------------------------------------
// k_exact: one wave per anchor; re-compute the SELECTED pair's distance
// exactly in f32, emit per-anchor loss and validity.
// ---------------------------------------------------------------------------
__global__ __launch_bounds__(256) void k_exact(const float* __restrict__ x,
                                               const float* __restrict__ sq,
                                               const float* __restrict__ dpos,
                                               const uint32* __restrict__ kn32,
                                               const uint32* __restrict__ ks32,
                                               float* __restrict__ loss,
                                               float* __restrict__ valid) {
    int wave = (blockIdx.x * blockDim.x + threadIdx.x) >> 6;
    int lane = threadIdx.x & 63;
    if (wave >= N) return;
    const int i = wave;

    uint32 kn = kn32[i], ks = ks32[i];
    bool has_neg = kn != KINIT;
    bool has_semi = ks != KINIT;
    float dp = dpos[i];
    bool has_pos = dp >= 0.0f;

    float l = 0.0f, v = 0.0f;
    if (has_pos && has_neg) {
        int j = (int)((has_semi ? ks : kn) & IDXMASK);
        float4 xi = reinterpret_cast<const float4*>(x + (size_t)i * D)[lane];
        float4 xj = reinterpret_cast<const float4*>(x + (size_t)j * D)[lane];
        float dotp = xi.x * xj.x + xi.y * xj.y + xi.z * xj.z + xi.w * xj.w;
        for (int m = 32; m >= 1; m >>= 1) dotp += __shfl_xor(dotp, m, 64);
        float sqd = fmaxf(sq[i] + sq[j] - 2.0f * dotp, 0.0f);
        float dn = sqd > 0.0f ? sqrtf(sqd) : 0.0f;
        l = fmaxf(dp - dn + MARGIN, 0.0f);
        v = 1.0f;
    }
    if (lane == 0) {
        loss[i] = l;
        valid[i] = v;
    }
}

// ---------------------------------------------------------------------------
// k_final: deterministic tree sum of loss/valid -> scalar.
// ---------------------------------------------------------------------------
__global__ __launch_bounds__(1024) void k_final(const float* __restrict__ loss,
                                                const float* __restrict__ valid,
                                                float* __restrict__ out) {
    __shared__ float ssum[1024];
    __shared__ float scnt[1024];
    int t = threadIdx.x;
    float s = 0.0f, cn = 0.0f;
    for (int i = t; i < N; i += 1024) {
        s += loss[i];
        cn += valid[i];
    }
    ssum[t] = s;
    scnt[t] = cn;
    __syncthreads();
    for (int off = 512; off >= 1; off >>= 1) {
        if (t < off) {
            ssum[t] += ssum[t + off];
            scnt[t] += scnt[t + off];
        }
        __syncthreads();
    }
    if (t == 0) out[0] = ssum[0] / scnt[0];
}

// ---------------------------------------------------------------------------
extern "C" void kernel_launch(void* const* d_in, const int* in_sizes, int n_in,
                              void* d_out, int out_size, void* d_ws, size_t ws_size,
                              hipStream_t stream) {
    const float* x = (const float*)d_in[0];
    const int* labels = (const int*)d_in[1];
    float* out = (float*)d_out;

    // ws layout (all 4B types):
    // sq[N] | dpos[N] | kn32[N] | ks32[N] | loss[N] | valid[N]
    // | cnt[512] | bkt[512*64] | hp[N*D] fp16 (4MB)
    // | pr_n[NTRI*128] | pr_s | pc_n | pc_s  (4 x 1.06MB)
    float* sq = (float*)d_ws;
    float* dpos = sq + N;
    uint32* kn32 = (uint32*)(dpos + N);
    uint32* ks32 = kn32 + N;
    float* loss = (float*)(ks32 + N);
    float* valid = loss + N;
    int* cnt = (int*)(valid + N);
    int* bkt = cnt + 512;
    _Float16* hp = (_Float16*)(bkt + 512 * BCAP);
    uint32* pr_n = (uint32*)(hp + (size_t)N * D);
    uint32* pr_s = pr_n + (size_t)NTRI * BM;
    uint32* pc_n = pr_s + (size_t)NTRI * BM;
    uint32* pc_s = pc_n + (size_t)NTRI * BM;

    hipMemsetAsync(cnt, 0, 512 * sizeof(int), stream);
    hipLaunchKernelGGL(k_conv, dim3(N * D / 4 / 256), dim3(256), 0, stream,
                       x, labels, hp, cnt, bkt);
    hipLaunchKernelGGL(k_dpos, dim3(N / 4), dim3(256), 0, stream,
                       x, labels, cnt, bkt, sq, dpos);
    hipLaunchKernelGGL(k_main, dim3(NTRI), dim3(256), 0, stream,
                       hp, labels, sq, dpos, pr_n, pr_s, pc_n, pc_s);
    hipLaunchKernelGGL(k_reduce, dim3(N / 256), dim3(256), 0, stream,
                       pr_n, pr_s, pc_n, pc_s, kn32, ks32);
    hipLaunchKernelGGL(k_exact, dim3(N / 4), dim3(256), 0, stream,
                       x, sq, dpos, kn32, ks32, loss, valid);
    hipLaunchKernelGGL(k_final, dim3(1), dim3(1024), 0, stream,
                       loss, valid, out);
}

// Round 10
// 123.918 us; speedup vs baseline: 1.5036x; 1.0751x over previous
//
#include <hip/hip_runtime.h>
#include <hip/hip_bf16.h>
#include <math.h>

#define N 8192
#define D 256
#define MARGIN 1.0f

#define BM 128
#define BN 128
#define NCH 4            // K-chunks of 64 fp16 elems (128B per row)
#define NB (N / BM)      // 64
#define NTRI (NB * (NB + 1) / 2)   // 2080
#define BCAP 64          // class bucket capacity

#define KINIT 0xFFFFFFFFu
#define QSCALE 131072.0f         // 2^17; fsq<=4 -> q <= 2^19 (clamped)
#define QMAX 524287.0f           // 2^19 - 1
#define IDXMASK 0x1FFFu          // 13 bits (N=8192)

typedef __attribute__((ext_vector_type(8))) _Float16 half8;
typedef __attribute__((ext_vector_type(4))) _Float16 half4;
typedef __attribute__((ext_vector_type(4))) float f32x4;
typedef unsigned int uint32;

__device__ __forceinline__ uint32 minu(uint32 a, uint32 b) { return a < b ? a : b; }

// ---------------------------------------------------------------------------
// k_conv: f32 -> fp16 plane + class buckets.
// ---------------------------------------------------------------------------
__global__ __launch_bounds__(256) void k_conv(const float* __restrict__ x,
                                              const int* __restrict__ labels,
                                              _Float16* __restrict__ hp,
                                              int* __restrict__ cnt,
                                              int* __restrict__ bkt) {
    int i = blockIdx.x * 256 + threadIdx.x;
    float4 v = reinterpret_cast<const float4*>(x)[i];
    half4 h;
    h[0] = (_Float16)v.x; h[1] = (_Float16)v.y;
    h[2] = (_Float16)v.z; h[3] = (_Float16)v.w;
    reinterpret_cast<half4*>(hp)[i] = h;
    if (i < N) {
        int lb = labels[i];
        int p = atomicAdd(&cnt[lb], 1);
        if (p < BCAP) bkt[lb * BCAP + p] = i;
    }
}

// ---------------------------------------------------------------------------
// k_dpos: one wave per anchor; exact f32 d_pos via class buckets.
// ---------------------------------------------------------------------------
__global__ __launch_bounds__(256) void k_dpos(const float* __restrict__ x,
                                              const int* __restrict__ labels,
                                              const int* __restrict__ cnt,
                                              const int* __restrict__ bkt,
                                              float* __restrict__ sq,
                                              float* __restrict__ dpos) {
    int wave = (blockIdx.x * blockDim.x + threadIdx.x) >> 6;
    int lane = threadIdx.x & 63;
    if (wave >= N) return;
    const int i = wave;

    float4 xi = reinterpret_cast<const float4*>(x + (size_t)i * D)[lane];
    float sqi = xi.x * xi.x + xi.y * xi.y + xi.z * xi.z + xi.w * xi.w;
    for (int m = 32; m >= 1; m >>= 1) sqi += __shfl_xor(sqi, m, 64);

    const int L = labels[i];
    int c = cnt[L]; if (c > BCAP) c = BCAP;
    float dp = -1.0f;

    for (int e = 0; e < c; ++e) {
        int j = bkt[L * BCAP + e];
        if (j == i) continue;
        float4 xj = reinterpret_cast<const float4*>(x + (size_t)j * D)[lane];
        float dotp = xi.x * xj.x + xi.y * xj.y + xi.z * xj.z + xi.w * xj.w;
        float sqjp = xj.x * xj.x + xj.y * xj.y + xj.z * xj.z + xj.w * xj.w;
        for (int m = 32; m >= 1; m >>= 1) {
            dotp += __shfl_xor(dotp, m, 64);
            sqjp += __shfl_xor(sqjp, m, 64);
        }
        float sqd = fmaxf(sqi + sqjp - 2.0f * dotp, 0.0f);
        float dist = sqd > 0.0f ? sqrtf(sqd) : 0.0f;
        dp = fmaxf(dp, dist);
    }

    if (lane == 0) {
        sq[i] = sqi;
        dpos[i] = dp;
    }
}

// ---------------------------------------------------------------------------
// k_main: symmetric fp16 MFMA GEMM, 8 waves (2x4 grid, 64x32 per wave).
// GEMM core = r9-proven staging/swizzle (linear gl_lds dest, pre-swizzled
// source, XOR'd ds_read, 0 conflicts), dbuf BK=64.
// Epilogue: unit-norm trick (sq==1): fsq = 2 - 2*acc; semi thresholds
// precomputed in acc-space (aLo < acc < aHi). 32-bit keys, shuffle-reduce,
// LDS cross-wave combine, plain partial stores (no global atomics).
// ---------------------------------------------------------------------------
__global__ __launch_bounds__(512) void k_main(const _Float16* __restrict__ hp,
                                              const int* __restrict__ labels,
                                              const float* __restrict__ dpos,
                                              uint32* __restrict__ pr_n,
                                              uint32* __restrict__ pr_s,
                                              uint32* __restrict__ pc_n,
                                              uint32* __restrict__ pc_s) {
    __shared__ char Abuf[2][BM * 128];   // 16 KB each
    __shared__ char Bbuf[2][BN * 128];
    __shared__ float rLo[BM], rHi[BM], cLo[BN], cHi[BN];
    __shared__ int rlab[BM], clab[BN];
    __shared__ uint32 tmpn[4][BM], tmps[4][BM];   // cross-wave combine

    const int t = threadIdx.x;
    int tb = blockIdx.x;
    // triangular decode: tb -> (by, bx), by <= bx
    int by = (int)((2 * NB + 1 - sqrtf((float)((2 * NB + 1) * (2 * NB + 1)) -
                                       8.0f * (float)tb)) * 0.5f);
    if (by < 0) by = 0;
    if (by > NB - 1) by = NB - 1;
    while (by > 0 && (by * NB - by * (by - 1) / 2) > tb) --by;
    while (((by + 1) * NB - (by + 1) * by / 2) <= tb) ++by;
    const int bx = by + (tb - (by * NB - by * (by - 1) / 2));
    const int r0 = by * BM, c0 = bx * BN;

    const int w = t >> 6, lane = t & 63;
    const int wr = w >> 2, wc = w & 3;   // 2x4 wave grid; per wave 64x32

    if (t < BM) {
        rlab[t] = labels[r0 + t];
        float dp = dpos[r0 + t];
        float dp2 = dp * dp;
        float dphi = dp + MARGIN;
        rHi[t] = (2.0f - dp2) * 0.5f;            // acc <  aHi  <=> sqd > dp2
        rLo[t] = (2.0f - dphi * dphi) * 0.5f;    // acc >  aLo  <=> sqd < dphi2
    } else if (t < 256) {
        int u = t - BM;
        clab[u] = labels[c0 + u];
        float dp = dpos[c0 + u];
        float dp2 = dp * dp;
        float dphi = dp + MARGIN;
        cHi[u] = (2.0f - dp2) * 0.5f;
        cLo[u] = (2.0f - dphi * dphi) * 0.5f;
    }

    f32x4 acc[4][2] = {};

    // staging: 16 chunks of 1KB per buffer; wave w stages chunks {w, w+8}.
    const int srow = lane >> 3;
    const int scol = ((lane & 7) ^ srow) << 3;   // fp16-elem offset

#define STAGE(bufA, bufB, k0e)                                                  \
    {                                                                           \
        _Pragma("unroll")                                                       \
        for (int q = 0; q < 2; ++q) {                                           \
            int chunk = q * 8 + w;                                              \
            int row = chunk * 8 + srow;                                         \
            const _Float16* gpa = hp + (size_t)(r0 + row) * D + (k0e) + scol;   \
            const _Float16* gpb = hp + (size_t)(c0 + row) * D + (k0e) + scol;   \
            char* lpa = (bufA) + chunk * 1024 + lane * 16;                      \
            char* lpb = (bufB) + chunk * 1024 + lane * 16;                      \
            __builtin_amdgcn_global_load_lds(                                   \
                (__attribute__((address_space(1))) void*)(void*)gpa,            \
                (__attribute__((address_space(3))) void*)lpa, 16, 0, 0);        \
            __builtin_amdgcn_global_load_lds(                                   \
                (__attribute__((address_space(1))) void*)(void*)gpb,            \
                (__attribute__((address_space(3))) void*)lpb, 16, 0, 0);        \
        }                                                                       \
    }

    STAGE(Abuf[0], Bbuf[0], 0);
    asm volatile("s_waitcnt vmcnt(0)" ::: "memory");
    __syncthreads();

    const int g2 = lane >> 4;
    const int lr = lane & 15;
    const int rsw = lr & 7;

#pragma unroll 1
    for (int s = 0; s < NCH; ++s) {
        const int cur = s & 1;
        if (s < NCH - 1) STAGE(Abuf[cur ^ 1], Bbuf[cur ^ 1], (s + 1) * 64);

#pragma unroll
        for (int kk = 0; kk < 2; ++kk) {
            const int cb = kk * 64 + (g2 << 4);
            half8 aF[4], bF[2];
#pragma unroll
            for (int m = 0; m < 4; ++m) {
                int ra = wr * 64 + m * 16 + lr;
                aF[m] = *reinterpret_cast<const half8*>(
                    Abuf[cur] + ra * 128 + (cb ^ (rsw << 4)));
            }
#pragma unroll
            for (int n = 0; n < 2; ++n) {
                int rb = wc * 32 + n * 16 + lr;
                bF[n] = *reinterpret_cast<const half8*>(
                    Bbuf[cur] + rb * 128 + (cb ^ (rsw << 4)));
            }
#pragma unroll
            for (int m = 0; m < 4; ++m)
#pragma unroll
                for (int n = 0; n < 2; ++n)
                    acc[m][n] = __builtin_amdgcn_mfma_f32_16x16x32_f16(
                        aF[m], bF[n], acc[m][n], 0, 0, 0);
        }
        __syncthreads();
    }
#undef STAGE

    // ---- epilogue: fsq = 2 - 2*acc (unit-norm), 32-bit keys, no atomics ----

    // row pass: per row, min over this wave's 32 cols
#pragma unroll
    for (int m = 0; m < 4; ++m) {
#pragma unroll
        for (int reg = 0; reg < 4; ++reg) {
            const int row = wr * 64 + m * 16 + g2 * 4 + reg;
            const int rl = rlab[row];
            const float aLo = rLo[row], aHi = rHi[row];
            uint32 kn = KINIT, ks = KINIT;
#pragma unroll
            for (int nn = 0; nn < 2; ++nn) {
                const int col = wc * 32 + nn * 16 + lr;
                float a = acc[m][nn][reg];
                float fsq = fmaxf(fmaf(-2.0f, a, 2.0f), 0.0f);
                uint32 key = ((uint32)fminf(fsq * QSCALE, QMAX) << 13) |
                             (uint32)(c0 + col);
                bool neq = (rl != clab[col]);
                kn = minu(kn, neq ? key : KINIT);
                bool semi = neq && (a > aLo) && (a < aHi);
                ks = minu(ks, semi ? key : KINIT);
            }
#pragma unroll
            for (int msk = 1; msk <= 8; msk <<= 1) {
                kn = minu(kn, (uint32)__shfl_xor((int)kn, msk, 64));
                ks = minu(ks, (uint32)__shfl_xor((int)ks, msk, 64));
            }
            if (lr == 0) {
                tmpn[wc][row] = kn;
                tmps[wc][row] = ks;
            }
        }
    }
    __syncthreads();
    if (t < BM) {
        uint32 a0 = minu(tmpn[0][t], tmpn[1][t]);
        uint32 a1 = minu(tmpn[2][t], tmpn[3][t]);
        pr_n[(size_t)tb * BM + t] = minu(a0, a1);
        uint32 b0 = minu(tmps[0][t], tmps[1][t]);
        uint32 b1 = minu(tmps[2][t], tmps[3][t]);
        pr_s[(size_t)tb * BM + t] = minu(b0, b1);
    }
    __syncthreads();

    // col pass: per col, min over this wave's 64 rows
#pragma unroll
    for (int n = 0; n < 2; ++n) {
        const int col = wc * 32 + n * 16 + lr;
        const int cl = clab[col];
        const float aLo = cLo[col], aHi = cHi[col];
        uint32 kn = KINIT, ks = KINIT;
#pragma unroll
        for (int m = 0; m < 4; ++m) {
#pragma unroll
            for (int reg = 0; reg < 4; ++reg) {
                const int row = wr * 64 + m * 16 + g2 * 4 + reg;
                float a = acc[m][n][reg];
                float fsq = fmaxf(fmaf(-2.0f, a, 2.0f), 0.0f);
                uint32 key = ((uint32)fminf(fsq * QSCALE, QMAX) << 13) |
                             (uint32)(r0 + row);
                bool neq = (cl != rlab[row]);
                kn = minu(kn, neq ? key : KINIT);
                bool semi = neq && (a > aLo) && (a < aHi);
                ks = minu(ks, semi ? key : KINIT);
            }
        }
        kn = minu(kn, (uint32)__shfl_xor((int)kn, 16, 64));
        kn = minu(kn, (uint32)__shfl_xor((int)kn, 32, 64));
        ks = minu(ks, (uint32)__shfl_xor((int)ks, 16, 64));
        ks = minu(ks, (uint32)__shfl_xor((int)ks, 32, 64));
        if (lane < 16) {
            tmpn[wr][col] = kn;
            tmps[wr][col] = ks;
        }
    }
    __syncthreads();
    if (t < BN) {
        pc_n[(size_t)tb * BN + t] = minu(tmpn[0][t], tmpn[1][t]);
        pc_s[(size_t)tb * BN + t] = minu(tmps[0][t], tmps[1][t]);
    }
}

// ---------------------------------------------------------------------------
// k_exact: one wave per anchor. Lanes split the 65x2 per-tile partials,
// shuffle-min to the final keys, broadcast the selected index, then
// recompute that pair's distance exactly in f32.
// ---------------------------------------------------------------------------
__global__ __launch_bounds__(256) void k_exact(const float* __restrict__ x,
                                               const float* __restrict__ sq,
                                               const float* __restrict__ dpos,
                                               const uint32* __restrict__ pr_n,
                                               const uint32* __restrict__ pr_s,
                                               const uint32* __restrict__ pc_n,
                                               const uint32* __restrict__ pc_s,
                                               float* __restrict__ loss,
                                               float* __restrict__ valid) {
    int wave = (blockIdx.x * blockDim.x + threadIdx.x) >> 6;
    int lane = threadIdx.x & 63;
    if (wave >= N) return;
    const int i = wave;
    const int q = i >> 7, r = i & 127;

    const int Lr = NB - q;              // row tiles (q, q..NB-1), consecutive
    const int base = q * NB - q * (q - 1) / 2;
    uint32 kn = KINIT, ks = KINIT;

    for (int u = lane; u < Lr + q + 1; u += 64) {
        size_t off;
        if (u < Lr) {
            off = (size_t)(base + u) * BM + r;
            kn = minu(kn, pr_n[off]);
            ks = minu(ks, pr_s[off]);
        } else {
            int byy = u - Lr;           // 0..q
            int tb2 = byy * NB - byy * (byy - 1) / 2 + (q - byy);
            off = (size_t)tb2 * BN + r;
            kn = minu(kn, pc_n[off]);
            ks = minu(ks, pc_s[off]);
        }
    }
    for (int msk = 1; msk <= 32; msk <<= 1) {
        kn = minu(kn, (uint32)__shfl_xor((int)kn, msk, 64));
        ks = minu(ks, (uint32)__shfl_xor((int)ks, msk, 64));
    }

    bool has_neg = kn != KINIT;
    bool has_semi = ks != KINIT;
    float dp = dpos[i];
    bool has_pos = dp >= 0.0f;

    float l = 0.0f, v = 0.0f;
    if (has_pos && has_neg) {
        int j = (int)((has_semi ? ks : kn) & IDXMASK);
        float4 xi = reinterpret_cast<const float4*>(x + (size_t)i * D)[lane];
        float4 xj = reinterpret_cast<const float4*>(x + (size_t)j * D)[lane];
        float dotp = xi.x * xj.x + xi.y * xj.y + xi.z * xj.z + xi.w * xj.w;
        for (int m = 32; m >= 1; m >>= 1) dotp += __shfl_xor(dotp, m, 64);
        float sqd = fmaxf(sq[i] + sq[j] - 2.0f * dotp, 0.0f);
        float dn = sqd > 0.0f ? sqrtf(sqd) : 0.0f;
        l = fmaxf(dp - dn + MARGIN, 0.0f);
        v = 1.0f;
    }
    if (lane == 0) {
        loss[i] = l;
        valid[i] = v;
    }
}

// ---------------------------------------------------------------------------
// k_final: deterministic tree sum of loss/valid -> scalar.
// ---------------------------------------------------------------------------
__global__ __launch_bounds__(1024) void k_final(const float* __restrict__ loss,
                                                const float* __restrict__ valid,
                                                float* __restrict__ out) {
    __shared__ float ssum[1024];
    __shared__ float scnt[1024];
    int t = threadIdx.x;
    float s = 0.0f, cn = 0.0f;
    for (int i = t; i < N; i += 1024) {
        s += loss[i];
        cn += valid[i];
    }
    ssum[t] = s;
    scnt[t] = cn;
    __syncthreads();
    for (int off = 512; off >= 1; off >>= 1) {
        if (t < off) {
            ssum[t] += ssum[t + off];
            scnt[t] += scnt[t + off];
        }
        __syncthreads();
    }
    if (t == 0) out[0] = ssum[0] / scnt[0];
}

// ---------------------------------------------------------------------------
extern "C" void kernel_launch(void* const* d_in, const int* in_sizes, int n_in,
                              void* d_out, int out_size, void* d_ws, size_t ws_size,
                              hipStream_t stream) {
    const float* x = (const float*)d_in[0];
    const int* labels = (const int*)d_in[1];
    float* out = (float*)d_out;

    // ws layout (4B types):
    // sq[N] | dpos[N] | loss[N] | valid[N] | cnt[512] | bkt[512*64]
    // | hp[N*D] fp16 (4MB) | pr_n[NTRI*128] | pr_s | pc_n | pc_s
    float* sq = (float*)d_ws;
    float* dpos = sq + N;
    float* loss = dpos + N;
    float* valid = loss + N;
    int* cnt = (int*)(valid + N);
    int* bkt = cnt + 512;
    _Float16* hp = (_Float16*)(bkt + 512 * BCAP);
    uint32* pr_n = (uint32*)(hp + (size_t)N * D);
    uint32* pr_s = pr_n + (size_t)NTRI * BM;
    uint32* pc_n = pr_s + (size_t)NTRI * BM;
    uint32* pc_s = pc_n + (size_t)NTRI * BM;

    hipMemsetAsync(cnt, 0, 512 * sizeof(int), stream);
    hipLaunchKernelGGL(k_conv, dim3(N * D / 4 / 256), dim3(256), 0, stream,
                       x, labels, hp, cnt, bkt);
    hipLaunchKernelGGL(k_dpos, dim3(N / 4), dim3(256), 0, stream,
                       x, labels, cnt, bkt, sq, dpos);
    hipLaunchKernelGGL(k_main, dim3(NTRI), dim3(512), 0, stream,
                       hp, labels, dpos, pr_n, pr_s, pc_n, pc_s);
    hipLaunchKernelGGL(k_exact, dim3(N / 4), dim3(256), 0, stream,
                       x, sq, dpos, pr_n, pr_s, pc_n, pc_s, loss, valid);
    hipLaunchKernelGGL(k_final, dim3(1), dim3(1024), 0, stream,
                       loss, valid, out);
}

// Round 11
// 118.888 us; speedup vs baseline: 1.5672x; 1.0423x over previous
//
#include <hip/hip_runtime.h>
#include <hip/hip_bf16.h>
#include <math.h>

#define N 8192
#define D 256
#define MARGIN 1.0f

#define BM 128
#define BN 128
#define NCH 4            // K-chunks of 64 fp16 elems (128B per row)
#define NB (N / BM)      // 64
#define NTRI (NB * (NB + 1) / 2)   // 2080
#define BCAP 64          // class bucket capacity

#define KINIT 0xFFFFFFFFu
#define QSCALE 131072.0f         // 2^17; fsq<=4 -> q <= 2^19 (clamped)
#define QMAX 524287.0f           // 2^19 - 1
#define IDXMASK 0x1FFFu          // 13 bits (N=8192)

typedef __attribute__((ext_vector_type(8))) _Float16 half8;
typedef __attribute__((ext_vector_type(4))) _Float16 half4;
typedef __attribute__((ext_vector_type(4))) float f32x4;
typedef unsigned int uint32;

__device__ __forceinline__ uint32 minu(uint32 a, uint32 b) { return a < b ? a : b; }

// ---------------------------------------------------------------------------
// k_conv: f32 -> fp16 plane + class buckets.
// ---------------------------------------------------------------------------
__global__ __launch_bounds__(256) void k_conv(const float* __restrict__ x,
                                              const int* __restrict__ labels,
                                              _Float16* __restrict__ hp,
                                              int* __restrict__ cnt,
                                              int* __restrict__ bkt) {
    int i = blockIdx.x * 256 + threadIdx.x;
    float4 v = reinterpret_cast<const float4*>(x)[i];
    half4 h;
    h[0] = (_Float16)v.x; h[1] = (_Float16)v.y;
    h[2] = (_Float16)v.z; h[3] = (_Float16)v.w;
    reinterpret_cast<half4*>(hp)[i] = h;
    if (i < N) {
        int lb = labels[i];
        int p = atomicAdd(&cnt[lb], 1);
        if (p < BCAP) bkt[lb * BCAP + p] = i;
    }
}

// ---------------------------------------------------------------------------
// k_dpos: one wave per anchor; exact f32 d_pos via class buckets.
// ---------------------------------------------------------------------------
__global__ __launch_bounds__(256) void k_dpos(const float* __restrict__ x,
                                              const int* __restrict__ labels,
                                              const int* __restrict__ cnt,
                                              const int* __restrict__ bkt,
                                              float* __restrict__ sq,
                                              float* __restrict__ dpos) {
    int wave = (blockIdx.x * blockDim.x + threadIdx.x) >> 6;
    int lane = threadIdx.x & 63;
    if (wave >= N) return;
    const int i = wave;

    float4 xi = reinterpret_cast<const float4*>(x + (size_t)i * D)[lane];
    float sqi = xi.x * xi.x + xi.y * xi.y + xi.z * xi.z + xi.w * xi.w;
    for (int m = 32; m >= 1; m >>= 1) sqi += __shfl_xor(sqi, m, 64);

    const int L = labels[i];
    int c = cnt[L]; if (c > BCAP) c = BCAP;
    float dp = -1.0f;

    for (int e = 0; e < c; ++e) {
        int j = bkt[L * BCAP + e];
        if (j == i) continue;
        float4 xj = reinterpret_cast<const float4*>(x + (size_t)j * D)[lane];
        float dotp = xi.x * xj.x + xi.y * xj.y + xi.z * xj.z + xi.w * xj.w;
        float sqjp = xj.x * xj.x + xj.y * xj.y + xj.z * xj.z + xj.w * xj.w;
        for (int m = 32; m >= 1; m >>= 1) {
            dotp += __shfl_xor(dotp, m, 64);
            sqjp += __shfl_xor(sqjp, m, 64);
        }
        float sqd = fmaxf(sqi + sqjp - 2.0f * dotp, 0.0f);
        float dist = sqd > 0.0f ? sqrtf(sqd) : 0.0f;
        dp = fmaxf(dp, dist);
    }

    if (lane == 0) {
        sq[i] = sqi;
        dpos[i] = dp;
    }
}

// ---------------------------------------------------------------------------
// k_main: symmetric fp16 MFMA GEMM, 8 waves (2x4), 64x32 per wave.
// NEW (r11): also accumulate the transposed product accT = mfma(bF, aF) --
// same register fragments, no extra LDS reads. In accT the ROW-anchor lies
// on the lane dimension, so the row-anchor min becomes an in-lane reg-min +
// 2 shuffles (like the col pass), cutting epilogue DS-shuffles 136 -> 24
// per wave. MFMA per wave 64 -> 128 (pipe was 90% idle).
// Epilogue: unit-norm fsq = 2-2*acc, acc-space semi thresholds, 32-bit
// (q<<13|idx) keys, plain partial stores (no global atomics).
// ---------------------------------------------------------------------------
__global__ __launch_bounds__(512) void k_main(const _Float16* __restrict__ hp,
                                              const int* __restrict__ labels,
                                              const float* __restrict__ dpos,
                                              uint32* __restrict__ pr_n,
                                              uint32* __restrict__ pr_s,
                                              uint32* __restrict__ pc_n,
                                              uint32* __restrict__ pc_s) {
    __shared__ char Abuf[2][BM * 128];   // 16 KB each
    __shared__ char Bbuf[2][BN * 128];
    __shared__ float rLo[BM], rHi[BM], cLo[BN], cHi[BN];
    __shared__ int rlab[BM], clab[BN];
    __shared__ uint32 tmpn[4][BM], tmps[4][BM];   // cross-wave combine

    const int t = threadIdx.x;
    int tb = blockIdx.x;
    // triangular decode: tb -> (by, bx), by <= bx
    int by = (int)((2 * NB + 1 - sqrtf((float)((2 * NB + 1) * (2 * NB + 1)) -
                                       8.0f * (float)tb)) * 0.5f);
    if (by < 0) by = 0;
    if (by > NB - 1) by = NB - 1;
    while (by > 0 && (by * NB - by * (by - 1) / 2) > tb) --by;
    while (((by + 1) * NB - (by + 1) * by / 2) <= tb) ++by;
    const int bx = by + (tb - (by * NB - by * (by - 1) / 2));
    const int r0 = by * BM, c0 = bx * BN;

    const int w = t >> 6, lane = t & 63;
    const int wr = w >> 2, wc = w & 3;   // 2x4 wave grid; per wave 64x32

    if (t < BM) {
        rlab[t] = labels[r0 + t];
        float dp = dpos[r0 + t];
        float dp2 = dp * dp;
        float dphi = dp + MARGIN;
        rHi[t] = (2.0f - dp2) * 0.5f;            // acc <  aHi  <=> sqd > dp2
        rLo[t] = (2.0f - dphi * dphi) * 0.5f;    // acc >  aLo  <=> sqd < dphi2
    } else if (t < 256) {
        int u = t - BM;
        clab[u] = labels[c0 + u];
        float dp = dpos[c0 + u];
        float dp2 = dp * dp;
        float dphi = dp + MARGIN;
        cHi[u] = (2.0f - dp2) * 0.5f;
        cLo[u] = (2.0f - dphi * dphi) * 0.5f;
    }

    f32x4 acc[4][2] = {};    // [m][n]: row = A-side, col = B-side
    f32x4 accT[2][4] = {};   // [n][m]: row = B-side, col = A-side

    // staging: 16 chunks of 1KB per buffer; wave w stages chunks {w, w+8}.
    const int srow = lane >> 3;
    const int scol = ((lane & 7) ^ srow) << 3;   // fp16-elem offset

#define STAGE(bufA, bufB, k0e)                                                  \
    {                                                                           \
        _Pragma("unroll")                                                       \
        for (int q = 0; q < 2; ++q) {                                           \
            int chunk = q * 8 + w;                                              \
            int row = chunk * 8 + srow;                                         \
            const _Float16* gpa = hp + (size_t)(r0 + row) * D + (k0e) + scol;   \
            const _Float16* gpb = hp + (size_t)(c0 + row) * D + (k0e) + scol;   \
            char* lpa = (bufA) + chunk * 1024 + lane * 16;                      \
            char* lpb = (bufB) + chunk * 1024 + lane * 16;                      \
            __builtin_amdgcn_global_load_lds(                                   \
                (__attribute__((address_space(1))) void*)(void*)gpa,            \
                (__attribute__((address_space(3))) void*)lpa, 16, 0, 0);        \
            __builtin_amdgcn_global_load_lds(                                   \
                (__attribute__((address_space(1))) void*)(void*)gpb,            \
                (__attribute__((address_space(3))) void*)lpb, 16, 0, 0);        \
        }                                                                       \
    }

    STAGE(Abuf[0], Bbuf[0], 0);
    asm volatile("s_waitcnt vmcnt(0)" ::: "memory");
    __syncthreads();

    const int g2 = lane >> 4;
    const int lr = lane & 15;
    const int rsw = lr & 7;

#pragma unroll 1
    for (int s = 0; s < NCH; ++s) {
        const int cur = s & 1;
        if (s < NCH - 1) STAGE(Abuf[cur ^ 1], Bbuf[cur ^ 1], (s + 1) * 64);

#pragma unroll
        for (int kk = 0; kk < 2; ++kk) {
            const int cb = kk * 64 + (g2 << 4);
            half8 aF[4], bF[2];
#pragma unroll
            for (int m = 0; m < 4; ++m) {
                int ra = wr * 64 + m * 16 + lr;
                aF[m] = *reinterpret_cast<const half8*>(
                    Abuf[cur] + ra * 128 + (cb ^ (rsw << 4)));
            }
#pragma unroll
            for (int n = 0; n < 2; ++n) {
                int rb = wc * 32 + n * 16 + lr;
                bF[n] = *reinterpret_cast<const half8*>(
                    Bbuf[cur] + rb * 128 + (cb ^ (rsw << 4)));
            }
#pragma unroll
            for (int m = 0; m < 4; ++m)
#pragma unroll
                for (int n = 0; n < 2; ++n)
                    acc[m][n] = __builtin_amdgcn_mfma_f32_16x16x32_f16(
                        aF[m], bF[n], acc[m][n], 0, 0, 0);
#pragma unroll
            for (int n = 0; n < 2; ++n)
#pragma unroll
                for (int m = 0; m < 4; ++m)
                    accT[n][m] = __builtin_amdgcn_mfma_f32_16x16x32_f16(
                        bF[n], aF[m], accT[n][m], 0, 0, 0);
        }
        __syncthreads();
    }
#undef STAGE

    // ---- epilogue: fsq = 2 - 2*acc (unit-norm), 32-bit keys, no atomics ----

    // row pass via accT: row-anchor = lane dim (wr*64+m*16+lr), cols in-lane
#pragma unroll
    for (int m = 0; m < 4; ++m) {
        const int row = wr * 64 + m * 16 + lr;
        const int rl = rlab[row];
        const float aLo = rLo[row], aHi = rHi[row];
        uint32 kn = KINIT, ks = KINIT;
#pragma unroll
        for (int n = 0; n < 2; ++n)
#pragma unroll
            for (int reg = 0; reg < 4; ++reg) {
                const int col = wc * 32 + n * 16 + g2 * 4 + reg;
                float a = accT[n][m][reg];
                float fsq = fmaxf(fmaf(-2.0f, a, 2.0f), 0.0f);
                uint32 key = ((uint32)fminf(fsq * QSCALE, QMAX) << 13) |
                             (uint32)(c0 + col);
                bool neq = (rl != clab[col]);
                kn = minu(kn, neq ? key : KINIT);
                bool semi = neq && (a > aLo) && (a < aHi);
                ks = minu(ks, semi ? key : KINIT);
            }
        kn = minu(kn, (uint32)__shfl_xor((int)kn, 16, 64));
        kn = minu(kn, (uint32)__shfl_xor((int)kn, 32, 64));
        ks = minu(ks, (uint32)__shfl_xor((int)ks, 16, 64));
        ks = minu(ks, (uint32)__shfl_xor((int)ks, 32, 64));
        if (g2 == 0) {
            tmpn[wc][row] = kn;
            tmps[wc][row] = ks;
        }
    }
    __syncthreads();
    if (t < BM) {
        uint32 a0 = minu(tmpn[0][t], tmpn[1][t]);
        uint32 a1 = minu(tmpn[2][t], tmpn[3][t]);
        pr_n[(size_t)tb * BM + t] = minu(a0, a1);
        uint32 b0 = minu(tmps[0][t], tmps[1][t]);
        uint32 b1 = minu(tmps[2][t], tmps[3][t]);
        pr_s[(size_t)tb * BM + t] = minu(b0, b1);
    }
    __syncthreads();

    // col pass via acc: col-anchor = lane dim (wc*32+n*16+lr), rows in-lane
#pragma unroll
    for (int n = 0; n < 2; ++n) {
        const int col = wc * 32 + n * 16 + lr;
        const int cl = clab[col];
        const float aLo = cLo[col], aHi = cHi[col];
        uint32 kn = KINIT, ks = KINIT;
#pragma unroll
        for (int m = 0; m < 4; ++m) {
#pragma unroll
            for (int reg = 0; reg < 4; ++reg) {
                const int row = wr * 64 + m * 16 + g2 * 4 + reg;
                float a = acc[m][n][reg];
                float fsq = fmaxf(fmaf(-2.0f, a, 2.0f), 0.0f);
                uint32 key = ((uint32)fminf(fsq * QSCALE, QMAX) << 13) |
                             (uint32)(r0 + row);
                bool neq = (cl != rlab[row]);
                kn = minu(kn, neq ? key : KINIT);
                bool semi = neq && (a > aLo) && (a < aHi);
                ks = minu(ks, semi ? key : KINIT);
            }
        }
        kn = minu(kn, (uint32)__shfl_xor((int)kn, 16, 64));
        kn = minu(kn, (uint32)__shfl_xor((int)kn, 32, 64));
        ks = minu(ks, (uint32)__shfl_xor((int)ks, 16, 64));
        ks = minu(ks, (uint32)__shfl_xor((int)ks, 32, 64));
        if (lane < 16) {
            tmpn[wr][col] = kn;
            tmps[wr][col] = ks;
        }
    }
    __syncthreads();
    if (t < BN) {
        pc_n[(size_t)tb * BN + t] = minu(tmpn[0][t], tmpn[1][t]);
        pc_s[(size_t)tb * BN + t] = minu(tmps[0][t], tmps[1][t]);
    }
}

// ---------------------------------------------------------------------------
// k_exact: one wave per anchor. Lanes split the 65x2 per-tile partials,
// shuffle-min to the final keys, broadcast the selected index, then
// recompute that pair's distance exactly in f32.
// ---------------------------------------------------------------------------
__global__ __launch_bounds__(256) void k_exact(const float* __restrict__ x,
                                               const float* __restrict__ sq,
                                               const float* __restrict__ dpos,
                                               const uint32* __restrict__ pr_n,
                                               const uint32* __restrict__ pr_s,
                                               const uint32* __restrict__ pc_n,
                                               const uint32* __restrict__ pc_s,
                                               float* __restrict__ loss,
                                               float* __restrict__ valid) {
    int wave = (blockIdx.x * blockDim.x + threadIdx.x) >> 6;
    int lane = threadIdx.x & 63;
    if (wave >= N) return;
    const int i = wave;
    const int q = i >> 7, r = i & 127;

    const int Lr = NB - q;              // row tiles (q, q..NB-1), consecutive
    const int base = q * NB - q * (q - 1) / 2;
    uint32 kn = KINIT, ks = KINIT;

    for (int u = lane; u < Lr + q + 1; u += 64) {
        size_t off;
        if (u < Lr) {
            off = (size_t)(base + u) * BM + r;
            kn = minu(kn, pr_n[off]);
            ks = minu(ks, pr_s[off]);
        } else {
            int byy = u - Lr;           // 0..q
            int tb2 = byy * NB - byy * (byy - 1) / 2 + (q - byy);
            off = (size_t)tb2 * BN + r;
            kn = minu(kn, pc_n[off]);
            ks = minu(ks, pc_s[off]);
        }
    }
    for (int msk = 1; msk <= 32; msk <<= 1) {
        kn = minu(kn, (uint32)__shfl_xor((int)kn, msk, 64));
        ks = minu(ks, (uint32)__shfl_xor((int)ks, msk, 64));
    }

    bool has_neg = kn != KINIT;
    bool has_semi = ks != KINIT;
    float dp = dpos[i];
    bool has_pos = dp >= 0.0f;

    float l = 0.0f, v = 0.0f;
    if (has_pos && has_neg) {
        int j = (int)((has_semi ? ks : kn) & IDXMASK);
        float4 xi = reinterpret_cast<const float4*>(x + (size_t)i * D)[lane];
        float4 xj = reinterpret_cast<const float4*>(x + (size_t)j * D)[lane];
        float dotp = xi.x * xj.x + xi.y * xj.y + xi.z * xj.z + xi.w * xj.w;
        for (int m = 32; m >= 1; m >>= 1) dotp += __shfl_xor(dotp, m, 64);
        float sqd = fmaxf(sq[i] + sq[j] - 2.0f * dotp, 0.0f);
        float dn = sqd > 0.0f ? sqrtf(sqd) : 0.0f;
        l = fmaxf(dp - dn + MARGIN, 0.0f);
        v = 1.0f;
    }
    if (lane == 0) {
        loss[i] = l;
        valid[i] = v;
    }
}

// ---------------------------------------------------------------------------
// k_final: deterministic wave-shuffle sum of loss/valid -> scalar.
// ---------------------------------------------------------------------------
__global__ __launch_bounds__(1024) void k_final(const float* __restrict__ loss,
                                                const float* __restrict__ valid,
                                                float* __restrict__ out) {
    __shared__ float wsum[16], wcnt[16];
    int t = threadIdx.x;
    float s = 0.0f, c = 0.0f;
    for (int i = t; i < N; i += 1024) {
        s += loss[i];
        c += valid[i];
    }
    for (int m = 1; m <= 32; m <<= 1) {
        s += __shfl_xor(s, m, 64);
        c += __shfl_xor(c, m, 64);
    }
    if ((t & 63) == 0) {
        wsum[t >> 6] = s;
        wcnt[t >> 6] = c;
    }
    __syncthreads();
    if (t < 64) {
        s = (t < 16) ? wsum[t] : 0.0f;
        c = (t < 16) ? wcnt[t] : 0.0f;
        for (int m = 1; m <= 8; m <<= 1) {
            s += __shfl_xor(s, m, 64);
            c += __shfl_xor(c, m, 64);
        }
        if (t == 0) out[0] = s / c;
    }
}

// ---------------------------------------------------------------------------
extern "C" void kernel_launch(void* const* d_in, const int* in_sizes, int n_in,
                              void* d_out, int out_size, void* d_ws, size_t ws_size,
                              hipStream_t stream) {
    const float* x = (const float*)d_in[0];
    const int* labels = (const int*)d_in[1];
    float* out = (float*)d_out;

    // ws layout (4B types):
    // sq[N] | dpos[N] | loss[N] | valid[N] | cnt[512] | bkt[512*64]
    // | hp[N*D] fp16 (4MB) | pr_n[NTRI*128] | pr_s | pc_n | pc_s
    float* sq = (float*)d_ws;
    float* dpos = sq + N;
    float* loss = dpos + N;
    float* valid = loss + N;
    int* cnt = (int*)(valid + N);
    int* bkt = cnt + 512;
    _Float16* hp = (_Float16*)(bkt + 512 * BCAP);
    uint32* pr_n = (uint32*)(hp + (size_t)N * D);
    uint32* pr_s = pr_n + (size_t)NTRI * BM;
    uint32* pc_n = pr_s + (size_t)NTRI * BM;
    uint32* pc_s = pc_n + (size_t)NTRI * BM;

    hipMemsetAsync(cnt, 0, 512 * sizeof(int), stream);
    hipLaunchKernelGGL(k_conv, dim3(N * D / 4 / 256), dim3(256), 0, stream,
                       x, labels, hp, cnt, bkt);
    hipLaunchKernelGGL(k_dpos, dim3(N / 4), dim3(256), 0, stream,
                       x, labels, cnt, bkt, sq, dpos);
    hipLaunchKernelGGL(k_main, dim3(NTRI), dim3(512), 0, stream,
                       hp, labels, dpos, pr_n, pr_s, pc_n, pc_s);
    hipLaunchKernelGGL(k_exact, dim3(N / 4), dim3(256), 0, stream,
                       x, sq, dpos, pr_n, pr_s, pc_n, pc_s, loss, valid);
    hipLaunchKernelGGL(k_final, dim3(1), dim3(1024), 0, stream,
                       loss, valid, out);
}